// Round 3
// baseline (746.904 us; speedup 1.0000x reference)
//
#include <hip/hip_runtime.h>
#include <hip/hip_bf16.h>
#include <stdint.h>

typedef __bf16 bf16_t;
typedef bf16_t bf16x8 __attribute__((ext_vector_type(8)));
typedef bf16_t bf16x4 __attribute__((ext_vector_type(4)));
typedef float  f32x4  __attribute__((ext_vector_type(4)));

#define B_  16
#define S_  1024
#define D_  1024
#define BS_ (B_ * S_)            // 16384
#define MAT_ (S_ * D_)           // 1048576 elems per batch matrix

// operand staging modes
#define M_BF16  0   // bf16 in global, m97 staging, direct bf16x8 frags
#define M_F32S  1   // fp32 in global, swizzled fp32 LDS, convert to single bf16
#define M_F32SP 2   // fp32 in global, swizzled fp32 LDS, split hi/lo bf16 (3-term GEMM)

__device__ __forceinline__ void async_load16(const void* g, void* l) {
    __builtin_amdgcn_global_load_lds((__attribute__((address_space(1))) void*)(g),
                                     (__attribute__((address_space(3))) void*)(l),
                                     16, 0, 0);
}

__device__ __forceinline__ void split_frag(f32x4 lo, f32x4 hi, bf16x8& h8, bf16x8& l8) {
#pragma unroll
    for (int e = 0; e < 4; ++e) {
        float x = lo[e]; bf16_t hx = (bf16_t)x;
        h8[e]     = hx;  l8[e]     = (bf16_t)(x - (float)hx);
        float y = hi[e]; bf16_t hy = (bf16_t)y;
        h8[e + 4] = hy;  l8[e + 4] = (bf16_t)(y - (float)hy);
    }
}

__device__ __forceinline__ void single_frag(f32x4 lo, f32x4 hi, bf16x8& h8) {
#pragma unroll
    for (int e = 0; e < 4; ++e) {
        h8[e]     = (bf16_t)lo[e];
        h8[e + 4] = (bf16_t)hi[e];
    }
}

// ---------------------------------------------------------------------------
// C[m,n] = sum_k A[m,k] * Bt[n,k], C fp32.
// 128x128 tile, BK=32, 4 waves of 64x64, mfma 16x16x32 bf16.
// fp32 operands: staged raw into LDS (8-row groups of 8x16B chunks, chunk
// position XOR-swizzled by row, +16B pad per group -> conflict-free reads),
// then converted to bf16 hi(/lo) fragments in registers.
// ---------------------------------------------------------------------------
template <int AM, int BM>
__global__ __launch_bounds__(256)
void gemm_bt(const void* __restrict__ Av, const void* __restrict__ Bv,
             float* __restrict__ C, int M, int N, int K,
             long strideA, long strideB, long strideC)
{
    constexpr int ABYTES = (AM == M_BF16) ? 8192 : 16640;   // 128x32 bf16 | 16 grp * 1040B
    constexpr int BBYTES = (BM == M_BF16) ? 8192 : 16640;
    __shared__ __attribute__((aligned(16))) char smem[ABYTES + BBYTES];
    char* lA = smem;
    char* lB = smem + ABYTES;

    const int b = blockIdx.z;
    const int tid  = threadIdx.x;
    const int wave = tid >> 6;
    const int lane = tid & 63;

    const int bm = blockIdx.x * 128;
    const int bn = blockIdx.y * 128;

    // per-lane invariant global bases
    const bf16_t* gAb = nullptr; const float* gAf = nullptr;
    const bf16_t* gBb = nullptr; const float* gBf = nullptr;
    if (AM == M_BF16)
        gAb = (const bf16_t*)Av + (long)b * strideA
            + (long)(bm + wave * 16 + (lane >> 2)) * K + (lane & 3) * 8;
    else
        gAf = (const float*)Av + (long)b * strideA
            + (long)(bm + (lane >> 3)) * K + ((lane & 7) ^ (lane >> 3)) * 4;
    if (BM == M_BF16)
        gBb = (const bf16_t*)Bv + (long)b * strideB
            + (long)(bn + wave * 16 + (lane >> 2)) * K + (lane & 3) * 8;
    else
        gBf = (const float*)Bv + (long)b * strideB
            + (long)(bn + (lane >> 3)) * K + ((lane & 7) ^ (lane >> 3)) * 4;

    const int fm   = lane & 15;
    const int quad = lane >> 4;
    const int wm   = (wave >> 1) * 64;
    const int wn   = (wave & 1) * 64;

    f32x4 acc[4][4] = {};

    for (int k0 = 0; k0 < K; k0 += 32) {
        __syncthreads();
        if (AM == M_BF16) {
            async_load16(gAb + k0,            lA + wave * 1024 + lane * 16);
            async_load16(gAb + k0 + 64 * K,   lA + 4096 + wave * 1024 + lane * 16);
        } else {
#pragma unroll
            for (int g = 0; g < 4; ++g)
                async_load16(gAf + k0 + (long)(wave * 4 + g) * 8 * K,
                             lA + (wave * 4 + g) * 1040 + lane * 16);
        }
        if (BM == M_BF16) {
            async_load16(gBb + k0,            lB + wave * 1024 + lane * 16);
            async_load16(gBb + k0 + 64 * K,   lB + 4096 + wave * 1024 + lane * 16);
        } else {
#pragma unroll
            for (int g = 0; g < 4; ++g)
                async_load16(gBf + k0 + (long)(wave * 4 + g) * 8 * K,
                             lB + (wave * 4 + g) * 1040 + lane * 16);
        }
        __syncthreads();

        bf16x8 aH[4], aL[4], bH[4], bL[4];
#pragma unroll
        for (int i = 0; i < 4; ++i) {
            {
                const int row = wm + i * 16 + fm;
                if (AM == M_BF16) {
                    aH[i] = *(const bf16x8*)(lA + row * 64 + quad * 16);
                } else {
                    const char* base = lA + (row >> 3) * 1040 + (row & 7) * 128;
                    f32x4 lo = *(const f32x4*)(base + (((2 * quad)     ^ (row & 7)) << 4));
                    f32x4 hi = *(const f32x4*)(base + (((2 * quad + 1) ^ (row & 7)) << 4));
                    if (AM == M_F32SP) split_frag(lo, hi, aH[i], aL[i]);
                    else               single_frag(lo, hi, aH[i]);
                }
            }
            {
                const int row = wn + i * 16 + fm;
                if (BM == M_BF16) {
                    bH[i] = *(const bf16x8*)(lB + row * 64 + quad * 16);
                } else {
                    const char* base = lB + (row >> 3) * 1040 + (row & 7) * 128;
                    f32x4 lo = *(const f32x4*)(base + (((2 * quad)     ^ (row & 7)) << 4));
                    f32x4 hi = *(const f32x4*)(base + (((2 * quad + 1) ^ (row & 7)) << 4));
                    if (BM == M_F32SP) split_frag(lo, hi, bH[i], bL[i]);
                    else               single_frag(lo, hi, bH[i]);
                }
            }
        }

#pragma unroll
        for (int i = 0; i < 4; ++i)
#pragma unroll
            for (int j = 0; j < 4; ++j) {
                acc[i][j] = __builtin_amdgcn_mfma_f32_16x16x32_bf16(aH[i], bH[j], acc[i][j], 0, 0, 0);
                if (AM == M_F32SP)
                    acc[i][j] = __builtin_amdgcn_mfma_f32_16x16x32_bf16(aL[i], bH[j], acc[i][j], 0, 0, 0);
                if (BM == M_F32SP)
                    acc[i][j] = __builtin_amdgcn_mfma_f32_16x16x32_bf16(aH[i], bL[j], acc[i][j], 0, 0, 0);
            }
    }

    float* Cb = C + (long)b * strideC;
#pragma unroll
    for (int i = 0; i < 4; ++i) {
        const int row0 = bm + wm + i * 16 + quad * 4;
#pragma unroll
        for (int j = 0; j < 4; ++j) {
            const int col = bn + wn + j * 16 + fm;
#pragma unroll
            for (int r = 0; r < 4; ++r)
                Cb[(long)(row0 + r) * N + col] = acc[i][j][r];
        }
    }
}

// ---------------------------------------------------------------------------
// Wt[e,d] = W[d,e]  (fp32 -> fp32)
// ---------------------------------------------------------------------------
__global__ void transpose_w(const float* __restrict__ W, float* __restrict__ Wt)
{
    __shared__ float tile[32][33];
    const int d0 = blockIdx.x * 32, e0 = blockIdx.y * 32;
    const int tx = threadIdx.x, ty = threadIdx.y;
    for (int r = ty; r < 32; r += 8)
        tile[r][tx] = W[(long)(d0 + r) * D_ + e0 + tx];
    __syncthreads();
    for (int r = ty; r < 32; r += 8)
        Wt[(long)(e0 + r) * D_ + d0 + tx] = tile[tx][r];
}

// ---------------------------------------------------------------------------
// audio softmax stats: per (b,t), max & sumexp over s (column-wise)
// ---------------------------------------------------------------------------
__global__ void col_stats_partial(const float* __restrict__ cc,
                                  float* __restrict__ Mp, float* __restrict__ Zp)
{
    const int b = blockIdx.x, tc = blockIdx.y, sc = blockIdx.z;
    const int t = tc * 256 + threadIdx.x;
    const float* p = cc + (long)b * MAT_ + (long)sc * 128 * S_ + t;
    float m = p[0], z = 1.f;
    for (int s = 1; s < 128; ++s) {
        float v = p[(long)s * S_];
        float nm = fmaxf(m, v);
        z = z * __expf(m - nm) + __expf(v - nm);
        m = nm;
    }
    const int idx = ((b * 8 + sc) << 10) + t;
    Mp[idx] = m; Zp[idx] = z;
}

__global__ void col_stats_combine(const float* __restrict__ Mp, const float* __restrict__ Zp,
                                  float* __restrict__ Mst, float* __restrict__ Zst)
{
    const int i = blockIdx.x * 256 + threadIdx.x;  // b*1024+t
    const int b = i >> 10, t = i & 1023;
    float m = Mp[((b * 8) << 10) + t], z = Zp[((b * 8) << 10) + t];
    for (int c = 1; c < 8; ++c) {
        float mc = Mp[((b * 8 + c) << 10) + t];
        float zc = Zp[((b * 8 + c) << 10) + t];
        float nm = fmaxf(m, mc);
        z = z * __expf(m - nm) + zc * __expf(mc - nm);
        m = nm;
    }
    Mst[i] = m; Zst[i] = z;
}

// ---------------------------------------------------------------------------
// visual softmax stats: per (b,s), max & sumexp over t (1 wave per row)
// ---------------------------------------------------------------------------
__global__ void row_stats(const float* __restrict__ cc,
                          float* __restrict__ Nst, float* __restrict__ Yst)
{
    const int row  = (blockIdx.x * 256 + threadIdx.x) >> 6;   // b*1024+s
    const int lane = threadIdx.x & 63;
    const float* p = cc + (long)row * S_;
    float m = p[lane], z = 1.f;
    for (int j = 1; j < 16; ++j) {
        float v = p[lane + j * 64];
        float nm = fmaxf(m, v);
        z = z * __expf(m - nm) + __expf(v - nm);
        m = nm;
    }
    for (int off = 32; off > 0; off >>= 1) {
        float mo = __shfl_down(m, off);
        float zo = __shfl_down(z, off);
        float nm = fmaxf(m, mo);
        z = z * __expf(m - nm) + zo * __expf(mo - nm);
        m = nm;
    }
    if (lane == 0) { Nst[row] = m; Yst[row] = z; }
}

// ---------------------------------------------------------------------------
// attA^T[b,t,s] = exp(cc[b,s,t]-M[b,t]) / Z[b,t]  (transpose + normalize)
// ---------------------------------------------------------------------------
__global__ void build_attA(const float* __restrict__ cc, const float* __restrict__ Mst,
                           const float* __restrict__ Zst, bf16_t* __restrict__ attA)
{
    __shared__ float tile[32][33];
    const int b = blockIdx.z;
    const int s0 = blockIdx.x * 32, t0 = blockIdx.y * 32;
    const int tx = threadIdx.x, ty = threadIdx.y;
    const float* src = cc + (long)b * MAT_;
    for (int r = ty; r < 32; r += 8)
        tile[r][tx] = src[(long)(s0 + r) * S_ + t0 + tx];
    __syncthreads();
    bf16_t* dst = attA + (long)b * MAT_;
    for (int r = ty; r < 32; r += 8) {
        const int t = t0 + r;
        const float m  = Mst[b * 1024 + t];
        const float rz = 1.f / Zst[b * 1024 + t];
        dst[(long)t * S_ + s0 + tx] = (bf16_t)(__expf(tile[tx][r] - m) * rz);
    }
}

// ---------------------------------------------------------------------------
// attV^T[b,s,t] = exp(cc[b,s,t]-N[b,s]) / Y[b,s]  (elementwise)
// ---------------------------------------------------------------------------
__global__ void build_attV(const float* __restrict__ cc, const float* __restrict__ Nst,
                           const float* __restrict__ Yst, bf16_t* __restrict__ attV)
{
    const long i = ((long)blockIdx.x * 256 + threadIdx.x) * 4;
    const int row = (int)(i >> 10);                           // b*1024+s
    const float m  = Nst[row];
    const float rz = 1.f / Yst[row];
    float4 v = *(const float4*)(cc + i);
    bf16x4 o;
    o[0] = (bf16_t)(__expf(v.x - m) * rz);
    o[1] = (bf16_t)(__expf(v.y - m) * rz);
    o[2] = (bf16_t)(__expf(v.z - m) * rz);
    o[3] = (bf16_t)(__expf(v.w - m) * rz);
    *(bf16x4*)(attV + i) = o;
}

// ---------------------------------------------------------------------------
extern "C" void kernel_launch(void* const* d_in, const int* in_sizes, int n_in,
                              void* d_out, int out_size, void* d_ws, size_t ws_size,
                              hipStream_t stream)
{
    const float* f1 = (const float*)d_in[0];   // [16,1024,1024] fp32
    const float* f2 = (const float*)d_in[1];   // [16,1024,1024] fp32
    const float* W  = (const float*)d_in[2];   // [1024,1024]    fp32

    float* out0 = (float*)d_out;               // final [16,1024,1024] fp32
    float* out1 = out0 + (long)B_ * MAT_;

    // fp32 scratch inside d_out (both fully dead before GEMM5/6 overwrite):
    float* a1 = out0;   // [16,1024,1024] fp32, dead after GEMM2
    float* cc = out1;   // [16,1024,1024] fp32 logits, dead after att builds

    char* w = (char*)d_ws;
    float*  Wt   = (float*) (w);                       //   4 MB
    bf16_t* attA = (bf16_t*)(w + (4l  << 20));         //  32 MB
    bf16_t* attV = (bf16_t*)(w + (36l << 20));         //  32 MB
    float*  Mp   = (float*) (w + (68l << 20));         // 512 KB
    float*  Zp   = Mp + 16 * 8 * 1024;                 // 512 KB
    float*  Mst  = Zp + 16 * 8 * 1024;
    float*  Zst  = Mst + BS_;
    float*  Nst  = Zst + BS_;
    float*  Yst  = Nst + BS_;

    // 0. Wt = W^T (fp32)
    transpose_w<<<dim3(32, 32), dim3(32, 8), 0, stream>>>(W, Wt);

    // 1. a1 = f1 @ Wt^T, split-bf16 x split-bf16 (fp32-accurate), batch in M
    gemm_bt<M_F32SP, M_F32SP><<<dim3(128, 8, 1), 256, 0, stream>>>(
        f1, Wt, a1, BS_, 1024, 1024, 0, 0, 0);

    // 2. cc[b] = a1[b] @ f2[b]^T, split x split (fp32-accurate logits)
    gemm_bt<M_F32SP, M_F32SP><<<dim3(8, 8, 16), 256, 0, stream>>>(
        a1, f2, cc, 1024, 1024, 1024, MAT_, MAT_, MAT_);

    // 3. softmax stats (both axes)
    col_stats_partial<<<dim3(16, 4, 8), 256, 0, stream>>>(cc, Mp, Zp);
    col_stats_combine<<<64, 256, 0, stream>>>(Mp, Zp, Mst, Zst);
    row_stats<<<4096, 256, 0, stream>>>(cc, Nst, Yst);

    // 4. attention matrices (bf16, stored transposed -> final GEMMs are A@B^T)
    build_attA<<<dim3(32, 32, 16), dim3(32, 8), 0, stream>>>(cc, Mst, Zst, attA);
    build_attV<<<16384, 256, 0, stream>>>(cc, Nst, Yst, attV);

    // 5. out0[b] = attA^T[b] @ f1[b]^T  (a1 scratch dead)
    gemm_bt<M_BF16, M_F32S><<<dim3(8, 8, 16), 256, 0, stream>>>(
        attA, f1, out0, 1024, 1024, 1024, MAT_, MAT_, MAT_);

    // 6. out1[b] = attV^T[b] @ f2[b]^T  (cc scratch dead)
    gemm_bt<M_BF16, M_F32S><<<dim3(8, 8, 16), 256, 0, stream>>>(
        attV, f2, out1, 1024, 1024, 1024, MAT_, MAT_, MAT_);
}

// Round 4
// 673.025 us; speedup vs baseline: 1.1098x; 1.1098x over previous
//
#include <hip/hip_runtime.h>
#include <hip/hip_bf16.h>
#include <stdint.h>

typedef __bf16 bf16_t;
typedef bf16_t bf16x8 __attribute__((ext_vector_type(8)));
typedef bf16_t bf16x4 __attribute__((ext_vector_type(4)));
typedef float  f32x4  __attribute__((ext_vector_type(4)));

#define B_  16
#define S_  1024
#define D_  1024
#define BS_ (B_ * S_)            // 16384
#define MAT_ (S_ * D_)           // 1048576 elems per batch matrix

__device__ __forceinline__ void async_load16(const void* g, void* l) {
    __builtin_amdgcn_global_load_lds((__attribute__((address_space(1))) void*)(g),
                                     (__attribute__((address_space(3))) void*)(l),
                                     16, 0, 0);
}

// ---------------------------------------------------------------------------
// C[m,n] = sum_k A[m,k]*Bt[n,k].  All operands bf16 (optionally hi/lo split
// pairs -> 3-term Markidis GEMM).  m97 structure: 128x128 tile, BK=32,
// 4 waves of 64x64, mfma 16x16x32 bf16, global_load_lds width-16 staging.
// OSP=0: C fp32.  OSP=1: C written as bf16 hi/lo pair (Ch, Cl).
// ---------------------------------------------------------------------------
template <int ASP, int BSP, int OSP>
__global__ __launch_bounds__(256)
void gemm_bt(const bf16_t* __restrict__ Ah, const bf16_t* __restrict__ Al,
             const bf16_t* __restrict__ Bh, const bf16_t* __restrict__ Bl,
             float* __restrict__ Cf, bf16_t* __restrict__ Ch, bf16_t* __restrict__ Cl,
             int M, int N, int K, long sA, long sB, long sC)
{
    constexpr int NTA = ASP ? 2 : 1;
    constexpr int NTB = BSP ? 2 : 1;
    __shared__ __attribute__((aligned(16))) bf16_t smem[(NTA + NTB) * 4096];
    char* lAh = (char*)smem;                    // 8192 B tile each
    char* lAl = lAh + 8192;                     // valid if ASP
    char* lBh = lAh + NTA * 8192;
    char* lBl = lBh + 8192;                     // valid if BSP

    const int b    = blockIdx.z;
    const int wave = threadIdx.x >> 6;
    const int lane = threadIdx.x & 63;

    const int bn = blockIdx.x * 128;            // N fast dim: A-tile L2 reuse
    const int bm = blockIdx.y * 128;

    // m97 staging: lane l -> row wave*16+(l>>2), 16B chunk (l&3)*8 elems
    const long aoff = (long)b * sA + (long)(bm + wave * 16 + (lane >> 2)) * K + (lane & 3) * 8;
    const long boff = (long)b * sB + (long)(bn + wave * 16 + (lane >> 2)) * K + (lane & 3) * 8;
    const bf16_t* gAh = Ah + aoff;
    const bf16_t* gAl = ASP ? (Al + aoff) : nullptr;
    const bf16_t* gBh = Bh + boff;
    const bf16_t* gBl = BSP ? (Bl + boff) : nullptr;

    const int fm   = lane & 15;
    const int quad = lane >> 4;
    const int wm   = (wave >> 1) * 64;
    const int wn   = (wave & 1) * 64;
    const int ldst = wave * 1024 + lane * 16;   // byte offset in tile (rows 0-63)

    f32x4 acc[4][4] = {};

    for (int k0 = 0; k0 < K; k0 += 32) {
        __syncthreads();
        async_load16(gAh + k0,          lAh + ldst);
        async_load16(gAh + k0 + 64 * K, lAh + 4096 + ldst);
        if constexpr (ASP) {
            async_load16(gAl + k0,          lAl + ldst);
            async_load16(gAl + k0 + 64 * K, lAl + 4096 + ldst);
        }
        async_load16(gBh + k0,          lBh + ldst);
        async_load16(gBh + k0 + 64 * K, lBh + 4096 + ldst);
        if constexpr (BSP) {
            async_load16(gBl + k0,          lBl + ldst);
            async_load16(gBl + k0 + 64 * K, lBl + 4096 + ldst);
        }
        __syncthreads();

        bf16x8 aH[4], aL[4], bH[4], bL[4];
#pragma unroll
        for (int i = 0; i < 4; ++i) {
            const int arow = wm + i * 16 + fm;
            const int brow = wn + i * 16 + fm;
            aH[i] = *(const bf16x8*)(lAh + arow * 64 + quad * 16);
            if constexpr (ASP) aL[i] = *(const bf16x8*)(lAl + arow * 64 + quad * 16);
            bH[i] = *(const bf16x8*)(lBh + brow * 64 + quad * 16);
            if constexpr (BSP) bL[i] = *(const bf16x8*)(lBl + brow * 64 + quad * 16);
        }

#pragma unroll
        for (int i = 0; i < 4; ++i)
#pragma unroll
            for (int j = 0; j < 4; ++j) {
                acc[i][j] = __builtin_amdgcn_mfma_f32_16x16x32_bf16(aH[i], bH[j], acc[i][j], 0, 0, 0);
                if constexpr (ASP)
                    acc[i][j] = __builtin_amdgcn_mfma_f32_16x16x32_bf16(aL[i], bH[j], acc[i][j], 0, 0, 0);
                if constexpr (BSP)
                    acc[i][j] = __builtin_amdgcn_mfma_f32_16x16x32_bf16(aH[i], bL[j], acc[i][j], 0, 0, 0);
            }
    }

    // epilogue: D[row = quad*4 + r][col = lane&15]
#pragma unroll
    for (int i = 0; i < 4; ++i) {
        const int row0 = bm + wm + i * 16 + quad * 4;
#pragma unroll
        for (int j = 0; j < 4; ++j) {
            const int col = bn + wn + j * 16 + fm;
#pragma unroll
            for (int r = 0; r < 4; ++r) {
                const long idx = (long)b * sC + (long)(row0 + r) * N + col;
                const float v = acc[i][j][r];
                if constexpr (OSP) {
                    const bf16_t h = (bf16_t)v;
                    Ch[idx] = h;
                    Cl[idx] = (bf16_t)(v - (float)h);
                } else {
                    Cf[idx] = v;
                }
            }
        }
    }
}

// ---------------------------------------------------------------------------
// fp32 -> bf16 hi/lo split (4 elems/thread)
// ---------------------------------------------------------------------------
__global__ void split_f32(const float* __restrict__ s,
                          bf16_t* __restrict__ h, bf16_t* __restrict__ l)
{
    const long i = ((long)blockIdx.x * 256 + threadIdx.x) * 4;
    float4 v = *(const float4*)(s + i);
    float a[4] = {v.x, v.y, v.z, v.w};
    bf16x4 hh, ll;
#pragma unroll
    for (int e = 0; e < 4; ++e) {
        const bf16_t hv = (bf16_t)a[e];
        hh[e] = hv;
        ll[e] = (bf16_t)(a[e] - (float)hv);
    }
    *(bf16x4*)(h + i) = hh;
    *(bf16x4*)(l + i) = ll;
}

// ---------------------------------------------------------------------------
// Wt[e,d] = split(W[d,e])
// ---------------------------------------------------------------------------
__global__ void transpose_split_w(const float* __restrict__ W,
                                  bf16_t* __restrict__ Wth, bf16_t* __restrict__ Wtl)
{
    __shared__ float tile[32][33];
    const int d0 = blockIdx.x * 32, e0 = blockIdx.y * 32;
    const int tx = threadIdx.x, ty = threadIdx.y;
    for (int r = ty; r < 32; r += 8)
        tile[r][tx] = W[(long)(d0 + r) * D_ + e0 + tx];
    __syncthreads();
    for (int r = ty; r < 32; r += 8) {
        const float v = tile[tx][r];
        const bf16_t h = (bf16_t)v;
        Wth[(long)(e0 + r) * D_ + d0 + tx] = h;
        Wtl[(long)(e0 + r) * D_ + d0 + tx] = (bf16_t)(v - (float)h);
    }
}

// ---------------------------------------------------------------------------
// audio softmax stats: per (b,t), max & sumexp over s (column-wise)
// ---------------------------------------------------------------------------
__global__ void col_stats_partial(const float* __restrict__ cc,
                                  float* __restrict__ Mp, float* __restrict__ Zp)
{
    const int b = blockIdx.x, tc = blockIdx.y, sc = blockIdx.z;
    const int t = tc * 256 + threadIdx.x;
    const float* p = cc + (long)b * MAT_ + (long)sc * 128 * S_ + t;
    float m = p[0], z = 1.f;
    for (int s = 1; s < 128; ++s) {
        float v = p[(long)s * S_];
        float nm = fmaxf(m, v);
        z = z * __expf(m - nm) + __expf(v - nm);
        m = nm;
    }
    const int idx = ((b * 8 + sc) << 10) + t;
    Mp[idx] = m; Zp[idx] = z;
}

__global__ void col_stats_combine(const float* __restrict__ Mp, const float* __restrict__ Zp,
                                  float* __restrict__ Mst, float* __restrict__ Zst)
{
    const int i = blockIdx.x * 256 + threadIdx.x;  // b*1024+t
    const int b = i >> 10, t = i & 1023;
    float m = Mp[((b * 8) << 10) + t], z = Zp[((b * 8) << 10) + t];
    for (int c = 1; c < 8; ++c) {
        float mc = Mp[((b * 8 + c) << 10) + t];
        float zc = Zp[((b * 8 + c) << 10) + t];
        float nm = fmaxf(m, mc);
        z = z * __expf(m - nm) + zc * __expf(mc - nm);
        m = nm;
    }
    Mst[i] = m; Zst[i] = z;
}

// ---------------------------------------------------------------------------
// visual softmax stats: per (b,s), max & sumexp over t (1 wave per row)
// ---------------------------------------------------------------------------
__global__ void row_stats(const float* __restrict__ cc,
                          float* __restrict__ Nst, float* __restrict__ Yst)
{
    const int row  = (blockIdx.x * 256 + threadIdx.x) >> 6;   // b*1024+s
    const int lane = threadIdx.x & 63;
    const float* p = cc + (long)row * S_;
    float m = p[lane], z = 1.f;
    for (int j = 1; j < 16; ++j) {
        float v = p[lane + j * 64];
        float nm = fmaxf(m, v);
        z = z * __expf(m - nm) + __expf(v - nm);
        m = nm;
    }
    for (int off = 32; off > 0; off >>= 1) {
        float mo = __shfl_down(m, off);
        float zo = __shfl_down(z, off);
        float nm = fmaxf(m, mo);
        z = z * __expf(m - nm) + zo * __expf(mo - nm);
        m = nm;
    }
    if (lane == 0) { Nst[row] = m; Yst[row] = z; }
}

// ---------------------------------------------------------------------------
// Fused attention-matrix build (one pass over cc):
//   attV[b,s,t] = exp(cc[b,s,t]-N[b,s]) / Y[b,s]        (same layout)
//   attA[b,t,s] = exp(cc[b,s,t]-M[b,t]) / Z[b,t]        (transposed)
// ---------------------------------------------------------------------------
__global__ void build_atts(const float* __restrict__ cc,
                           const float* __restrict__ Mst, const float* __restrict__ Zst,
                           const float* __restrict__ Nst, const float* __restrict__ Yst,
                           bf16_t* __restrict__ attA, bf16_t* __restrict__ attV)
{
    __shared__ float tile[32][33];
    const int b = blockIdx.z;
    const int s0 = blockIdx.x * 32, t0 = blockIdx.y * 32;
    const int tx = threadIdx.x, ty = threadIdx.y;
    const float* src = cc + (long)b * MAT_;
    bf16_t* dV = attV + (long)b * MAT_;
    bf16_t* dA = attA + (long)b * MAT_;
    for (int r = ty; r < 32; r += 8) {
        const int s = s0 + r;
        const float v = src[(long)s * S_ + t0 + tx];
        tile[r][tx] = v;
        dV[(long)s * S_ + t0 + tx] =
            (bf16_t)(__expf(v - Nst[b * 1024 + s]) * (1.f / Yst[b * 1024 + s]));
    }
    __syncthreads();
    for (int r = ty; r < 32; r += 8) {
        const int t = t0 + r;
        const float m  = Mst[b * 1024 + t];
        const float rz = 1.f / Zst[b * 1024 + t];
        dA[(long)t * S_ + s0 + tx] = (bf16_t)(__expf(tile[tx][r] - m) * rz);
    }
}

// ---------------------------------------------------------------------------
extern "C" void kernel_launch(void* const* d_in, const int* in_sizes, int n_in,
                              void* d_out, int out_size, void* d_ws, size_t ws_size,
                              hipStream_t stream)
{
    const float* f1 = (const float*)d_in[0];   // [16,1024,1024] fp32
    const float* f2 = (const float*)d_in[1];   // [16,1024,1024] fp32
    const float* W  = (const float*)d_in[2];   // [1024,1024]    fp32

    float* out0 = (float*)d_out;               // final fp32 outputs
    float* out1 = out0 + (long)B_ * MAT_;

    // d_out reuse (regions fully dead before final overwrite):
    bf16_t* a1h = (bf16_t*)out0;               // 32 MB, dead after G2
    bf16_t* a1l = a1h + (long)B_ * MAT_;       // 32 MB, dead after G2
    bf16_t* Wth = (bf16_t*)out1;               //  2 MB, dead after G1
    bf16_t* Wtl = Wth + (long)MAT_;            //  2 MB, dead after G1
    float*  cc  = out1;                        // 64 MB fp32 logits, dead after builds

    char* w = (char*)d_ws;                     // total ws use: ~129.3 MB
    bf16_t* f1h  = (bf16_t*)(w);               // 32 MB  (G1, G5)
    bf16_t* f2h  = (bf16_t*)(w + (32l << 20)); // 32 MB  (G2, G6)
    bf16_t* f1l  = (bf16_t*)(w + (64l << 20)); // 32 MB  (G1 only)
    bf16_t* f2l  = (bf16_t*)(w + (96l << 20)); // 32 MB  (G2 only)
    bf16_t* attA = f1l;                        // aliases f1l (dead after G1)
    bf16_t* attV = f2l;                        // aliases f2l (dead after G2)
    float*  Mp   = (float*)(w + (128l << 20)); // 512 KB
    float*  Zp   = Mp + 16 * 8 * 1024;         // 512 KB
    float*  Mst  = Zp + 16 * 8 * 1024;
    float*  Zst  = Mst + BS_;
    float*  Nst  = Zst + BS_;
    float*  Yst  = Nst + BS_;

    // 0. pre-split all fp32 operands to bf16 hi/lo
    split_f32<<<16384, 256, 0, stream>>>(f1, f1h, f1l);
    split_f32<<<16384, 256, 0, stream>>>(f2, f2h, f2l);
    transpose_split_w<<<dim3(32, 32), dim3(32, 8), 0, stream>>>(W, Wth, Wtl);

    // 1. a1 = f1 @ Wt^T (3-term split), output as bf16 hi/lo into out0 region
    gemm_bt<1, 1, 1><<<dim3(8, 128, 1), 256, 0, stream>>>(
        f1h, f1l, Wth, Wtl, nullptr, a1h, a1l, BS_, 1024, 1024, 0, 0, 0);

    // 2. cc[b] = a1[b] @ f2[b]^T (3-term split), fp32 logits into out1 region
    gemm_bt<1, 1, 0><<<dim3(8, 8, 16), 256, 0, stream>>>(
        a1h, a1l, f2h, f2l, cc, nullptr, nullptr, 1024, 1024, 1024, MAT_, MAT_, MAT_);

    // 3. softmax stats (both axes)
    col_stats_partial<<<dim3(16, 4, 8), 256, 0, stream>>>(cc, Mp, Zp);
    col_stats_combine<<<64, 256, 0, stream>>>(Mp, Zp, Mst, Zst);
    row_stats<<<4096, 256, 0, stream>>>(cc, Nst, Yst);

    // 4. fused attention-matrix build (one cc pass)
    build_atts<<<dim3(32, 32, 16), dim3(32, 8), 0, stream>>>(
        cc, Mst, Zst, Nst, Yst, attA, attV);

    // 5. out0[b] = attA^T[b] @ f1[b]^T   (a1h/a1l dead)
    gemm_bt<0, 0, 0><<<dim3(8, 8, 16), 256, 0, stream>>>(
        attA, nullptr, f1h, nullptr, out0, nullptr, nullptr,
        1024, 1024, 1024, MAT_, MAT_, MAT_);

    // 6. out1[b] = attV^T[b] @ f2[b]^T   (cc dead)
    gemm_bt<0, 0, 0><<<dim3(8, 8, 16), 256, 0, stream>>>(
        attV, nullptr, f2h, nullptr, out1, nullptr, nullptr,
        1024, 1024, 1024, MAT_, MAT_, MAT_);
}